// Round 9
// baseline (461.739 us; speedup 1.0000x reference)
//
#include <hip/hip_runtime.h>

#define TPB 256
#define NBLK_EDGE 1024         // blocks for hist/reorder; chunking must match between them
#define CHUNKE 8192            // max edges per reorder block
#define BIN_SHIFT 8
#define BIN_SIZE 256           // nodes per bin
#define MAXK 2048              // max bins (N=500K -> K=1954)
#define ROW_BITS 19            // N=500,000 < 2^19
#define ROW_MASK ((1u << ROW_BITS) - 1)
#define Q_SHIFT 17             // source quarter = row>>17 (131072 nodes = 2.1MB of g0, fits 4MiB L2)
#define NKEY 1024              // binsort keys: (lc<<2)|quarter
#define CAP 8192               // binsort LDS staging (32KB); mean bin = 4094 edges (+64 sigma)

typedef _Float16 half8  __attribute__((ext_vector_type(8)));
typedef _Float16 half2v __attribute__((ext_vector_type(2)));

__global__ void k_zero_int(int* __restrict__ p, int n) {
    int i = blockIdx.x * blockDim.x + threadIdx.x;
    if (i < n) p[i] = 0;
}

// Per-block LDS histogram of col>>BIN_SHIFT; persists per-block rows in both
// layouts: cntB (block-major, reload in k_reorder) and cntT (bin-major, for
// k_colscan). No global atomics.
__global__ void k_hist(const int* __restrict__ col, int E, int chunk, int K,
                       int* __restrict__ cntB, int* __restrict__ cntT) {
    __shared__ int lh[MAXK];
    int blk = blockIdx.x;
    for (int k = threadIdx.x; k < MAXK; k += blockDim.x) lh[k] = 0;
    __syncthreads();
    int s = blk * chunk, e_ = min(s + chunk, E);
    for (int e = s + threadIdx.x; e < e_; e += blockDim.x)
        atomicAdd(&lh[col[e] >> BIN_SHIFT], 1);
    __syncthreads();
    for (int k = threadIdx.x; k < MAXK; k += blockDim.x) {
        int v = lh[k];
        cntB[(size_t)blk * MAXK + k] = v;
        cntT[(size_t)k * NBLK_EDGE + blk] = v;
    }
}

// Per-bin exclusive scan over the NBLK_EDGE per-block counts (in-place) and
// per-bin total -> ghist. One block per bin, coalesced row access.
__global__ void k_colscan(int* __restrict__ cntT, int* __restrict__ ghist) {
    __shared__ int part[256];
    int b = blockIdx.x, tid = threadIdx.x;
    size_t base = (size_t)b * NBLK_EDGE;
    int t4 = tid * 4;
    int c0 = cntT[base + t4], c1 = cntT[base + t4 + 1],
        c2 = cntT[base + t4 + 2], c3 = cntT[base + t4 + 3];
    int sum = c0 + c1 + c2 + c3;
    part[tid] = sum;
    __syncthreads();
    for (int off = 1; off < 256; off <<= 1) {
        int v = (tid >= off) ? part[tid - off] : 0;
        __syncthreads();
        part[tid] += v;
        __syncthreads();
    }
    int excl = part[tid] - sum;
    cntT[base + t4]     = excl;
    cntT[base + t4 + 1] = excl + c0;
    cntT[base + t4 + 2] = excl + c0 + c1;
    cntT[base + t4 + 3] = excl + c0 + c1 + c2;
    if (tid == 255) ghist[b] = part[255];  // bin total
}

// Exclusive scan over K<=MAXK bins: 1024 threads, 2 consecutive elems/thread.
__global__ void k_scan(const int* __restrict__ ghist, int K, int* __restrict__ binBase) {
    __shared__ int part[1024];
    int tid = threadIdx.x;
    int t2 = tid * 2;
    int a = (t2 < K) ? ghist[t2] : 0;
    int b = (t2 + 1 < K) ? ghist[t2 + 1] : 0;
    int sum = a + b;
    part[tid] = sum;
    __syncthreads();
    for (int off = 1; off < 1024; off <<= 1) {
        int v = (tid >= off) ? part[tid - off] : 0;
        __syncthreads();
        part[tid] += v;
        __syncthreads();
    }
    int excl = part[tid] - sum;
    if (t2 < K)     binBase[t2] = excl;
    if (t2 + 1 < K) binBase[t2 + 1] = excl + a;
    if (tid == 1023) binBase[K] = part[1023];  // == E
}

// Reorder with LOCAL SORT: place the block's chunk bin-sorted in LDS, then
// write out in contiguous per-bin runs so stores coalesce. Placement bases are
// precomputed (binBase + scanned cntT): no global atomics.
__global__ void __launch_bounds__(256) k_reorder(
        const int* __restrict__ row, const int* __restrict__ col,
        int E, int chunk, int K,
        const int* __restrict__ binBase, const int* __restrict__ cntB,
        const int* __restrict__ cntT, unsigned* __restrict__ packed) {
    __shared__ unsigned sorted[CHUNKE];       // 32 KB
    __shared__ unsigned short sbin[CHUNKE];   // 16 KB
    __shared__ int lcur[MAXK], lbase[MAXK], gbase[MAXK];  // 24 KB
    __shared__ int part[256];
    int blk = blockIdx.x, tid = threadIdx.x;
    int s = blk * chunk, e_ = min(s + chunk, E), len = e_ - s;
    // local exclusive scan of this block's per-bin counts (8 keys/thread)
    int t8 = tid * 8;
    size_t bb = (size_t)blk * MAXK;
    int c[8], sum = 0;
#pragma unroll
    for (int j = 0; j < 8; ++j) { c[j] = cntB[bb + t8 + j]; sum += c[j]; }
    part[tid] = sum;
    __syncthreads();
    for (int off = 1; off < 256; off <<= 1) {
        int v = (tid >= off) ? part[tid - off] : 0;
        __syncthreads();
        part[tid] += v;
        __syncthreads();
    }
    int run = part[tid] - sum;
#pragma unroll
    for (int j = 0; j < 8; ++j) {
        lbase[t8 + j] = run;
        lcur[t8 + j] = run;
        run += c[j];
    }
    for (int k = tid; k < K; k += blockDim.x)
        gbase[k] = binBase[k] + cntT[(size_t)k * NBLK_EDGE + blk];
    __syncthreads();
    // placement: bin-sorted staging in LDS (1 LDS atomic per edge)
    for (int i = tid; i < len; i += blockDim.x) {
        int cc = col[s + i];
        int b = cc >> BIN_SHIFT;
        int slot = atomicAdd(&lcur[b], 1);
        sorted[slot] = ((unsigned)(cc & (BIN_SIZE - 1)) << ROW_BITS) | (unsigned)row[s + i];
        sbin[slot] = (unsigned short)b;
    }
    __syncthreads();
    // coalesced run write-out
    for (int i = tid; i < len; i += blockDim.x) {
        int b = sbin[i];
        packed[gbase[b] + (i - lbase[b])] = sorted[i];
    }
}

// Counting sort by composite key (dest node, src quarter) within each bin.
// cnt gives per-node degree (dinv) AND per-(node,quarter) segment bases
// (keyptr), enabling L2-windowed phased gathers. In-place via LDS staging;
// oversized bins (>CAP) stage through global scratch (ticketed).
__global__ void __launch_bounds__(1024) k_binsort_deg(
        unsigned* __restrict__ packed, const int* __restrict__ binBase,
        unsigned* __restrict__ scratch, int* __restrict__ scratchCur,
        float* __restrict__ dinv, int* __restrict__ keyptr, int N, int E, int K) {
    __shared__ unsigned buf[CAP];      // 32 KB
    __shared__ int cnt[NKEY], cur[NKEY];
    __shared__ int sbShared;
    int tid = threadIdx.x;
    int bin = blockIdx.x;
    int s = binBase[bin], t = binBase[bin + 1];
    int len = t - s;
    bool fast = (len <= CAP);
    cnt[tid] = 0;
    if (!fast && tid == 0) sbShared = atomicAdd(scratchCur, len);
    __syncthreads();
    unsigned* stage = fast ? buf : (scratch + sbShared);
    // stage + composite-key count
    for (int i = tid; i < len; i += blockDim.x) {
        unsigned v = packed[s + i];
        stage[i] = v;
        int k = (int)((v >> ROW_BITS) << 2) | (int)((v & ROW_MASK) >> Q_SHIFT);
        atomicAdd(&cnt[k], 1);
    }
    __syncthreads();
    // inclusive scan of cnt into cur (cnt preserved)
    int val = cnt[tid];
    cur[tid] = val;
    __syncthreads();
    for (int off = 1; off < NKEY; off <<= 1) {
        int v = (tid >= off) ? cur[tid - off] : 0;
        __syncthreads();
        cur[tid] += v;
        __syncthreads();
    }
    int base = bin << BIN_SHIFT;
    // keyptr: one entry per key
    {
        int node = base + (tid >> 2);
        if (node < N) keyptr[((size_t)bin << 10) + tid] = s + cur[tid] - cnt[tid];
    }
    // degree -> dinv (one thread per node)
    if (tid < BIN_SIZE) {
        int node = base + tid;
        if (node < N) {
            int deg = cnt[4 * tid] + cnt[4 * tid + 1] + cnt[4 * tid + 2] + cnt[4 * tid + 3];
            dinv[node] = rsqrtf((float)(deg + 1));  // +1 self-loop
        }
    }
    if (bin == K - 1 && tid == 0) keyptr[(size_t)4 * N] = E;  // sentinel
    __syncthreads();
    cur[tid] -= cnt[tid];  // exclusive: running placement cursor
    __syncthreads();
    for (int i = tid; i < len; i += blockDim.x) {
        unsigned v = stage[i];
        int k = (int)((v >> ROW_BITS) << 2) | (int)((v & ROW_MASK) >> Q_SHIFT);
        int slot = atomicAdd(&cur[k], 1);
        packed[s + slot] = v;
    }
}

// g0 = f16(dinv * (x @ W1)) — pure per-node, no edge work.
__global__ void k_node1(const float* __restrict__ x, const float* __restrict__ W1,
                        const float* __restrict__ dinv_arr, half8* __restrict__ g0, int N) {
    int i = blockIdx.x * blockDim.x + threadIdx.x;
    if (i >= N) return;
    float di = dinv_arr[i];
    const float4* xv = (const float4*)(x + (size_t)i * 16);
    float4 a0 = xv[0], a1 = xv[1], a2 = xv[2], a3 = xv[3];
    float xl[16] = {a0.x, a0.y, a0.z, a0.w, a1.x, a1.y, a1.z, a1.w,
                    a2.x, a2.y, a2.z, a2.w, a3.x, a3.y, a3.z, a3.w};
    float h[8];
#pragma unroll
    for (int j = 0; j < 8; ++j) h[j] = 0.0f;
#pragma unroll
    for (int k = 0; k < 16; ++k) {
        float xk = xl[k];
#pragma unroll
        for (int j = 0; j < 8; ++j) h[j] += xk * W1[k * 8 + j];
    }
    half8 g;
#pragma unroll
    for (int j = 0; j < 8; ++j) g[j] = (_Float16)(di * h[j]);
    g0[i] = g;
}

// Phased CSR gather layer 1: phase q only gathers sources in quarter q
// (2.1MB g0 window -> per-XCD L2 resident). Partial sums carried in accA
// (coalesced f32). q==3 adds self-loop, applies dinv + MLP -> g1.
__global__ void k_gather1_phase(const unsigned* __restrict__ packed,
                                const int* __restrict__ keyptr,
                                const half8* __restrict__ g0,
                                const float* __restrict__ dinv_arr,
                                const float* __restrict__ b1,
                                const float* __restrict__ W2,
                                float* __restrict__ accA,
                                half2v* __restrict__ g1, int N, int q) {
    int i = blockIdx.x * blockDim.x + threadIdx.x;
    if (i >= N) return;
    int s = keyptr[4 * i + q], t = keyptr[4 * i + q + 1];
    float acc[8];
    if (q == 0) {
#pragma unroll
        for (int j = 0; j < 8; ++j) acc[j] = 0.0f;
    } else {
        const float4* av = (const float4*)(accA + (size_t)i * 8);
        float4 lo = av[0], hi = av[1];
        acc[0] = lo.x; acc[1] = lo.y; acc[2] = lo.z; acc[3] = lo.w;
        acc[4] = hi.x; acc[5] = hi.y; acc[6] = hi.z; acc[7] = hi.w;
    }
    int e = s;
    for (; e + 4 <= t; e += 4) {
        unsigned p0 = packed[e], p1 = packed[e + 1], p2 = packed[e + 2], p3 = packed[e + 3];
        half8 v0 = g0[p0 & ROW_MASK];
        half8 v1 = g0[p1 & ROW_MASK];
        half8 v2 = g0[p2 & ROW_MASK];
        half8 v3 = g0[p3 & ROW_MASK];
#pragma unroll
        for (int j = 0; j < 8; ++j)
            acc[j] += (float)v0[j] + (float)v1[j] + (float)v2[j] + (float)v3[j];
    }
    for (; e < t; ++e) {
        half8 v = g0[packed[e] & ROW_MASK];
#pragma unroll
        for (int j = 0; j < 8; ++j) acc[j] += (float)v[j];
    }
    if (q < 3) {
        float4* av = (float4*)(accA + (size_t)i * 8);
        av[0] = make_float4(acc[0], acc[1], acc[2], acc[3]);
        av[1] = make_float4(acc[4], acc[5], acc[6], acc[7]);
    } else {
        half8 self = g0[i];
        float di = dinv_arr[i];
        float o0 = 0.0f, o1 = 0.0f;
#pragma unroll
        for (int j = 0; j < 8; ++j) {
            float hj = fmaxf(di * (acc[j] + (float)self[j]) + b1[j], 0.0f);
            o0 += hj * W2[j * 2 + 0];
            o1 += hj * W2[j * 2 + 1];
        }
        half2v g;
        g.x = (_Float16)(di * o0);
        g.y = (_Float16)(di * o1);
        g1[i] = g;
    }
}

// CSR gather layer 2 (g1 = 2MB, L2-resident) fused with log-softmax epilogue.
__global__ void k_gather2_final(const unsigned* __restrict__ packed,
                                const int* __restrict__ keyptr,
                                const half2v* __restrict__ g1,
                                const float* __restrict__ dinv_arr,
                                const float* __restrict__ b2,
                                float* __restrict__ out, int N) {
    int i = blockIdx.x * blockDim.x + threadIdx.x;
    if (i >= N) return;
    int s = keyptr[4 * i], t = keyptr[4 * i + 4];
    half2v sg = g1[i];
    float a0 = (float)sg.x, a1 = (float)sg.y;  // self-loop
    int e = s;
    for (; e + 4 <= t; e += 4) {
        unsigned p0 = packed[e], p1 = packed[e + 1], p2 = packed[e + 2], p3 = packed[e + 3];
        half2v v0 = g1[p0 & ROW_MASK];
        half2v v1 = g1[p1 & ROW_MASK];
        half2v v2 = g1[p2 & ROW_MASK];
        half2v v3 = g1[p3 & ROW_MASK];
        a0 += (float)v0.x + (float)v1.x + (float)v2.x + (float)v3.x;
        a1 += (float)v0.y + (float)v1.y + (float)v2.y + (float)v3.y;
    }
    for (; e < t; ++e) {
        half2v v = g1[packed[e] & ROW_MASK];
        a0 += (float)v.x;
        a1 += (float)v.y;
    }
    float di = dinv_arr[i];
    float o0 = di * a0 + b2[0];
    float o1 = di * a1 + b2[1];
    float m = fmaxf(o0, o1);
    float lse = m + logf(expf(o0 - m) + expf(o1 - m));
    ((float2*)out)[i] = make_float2(o0 - lse, o1 - lse);
}

extern "C" void kernel_launch(void* const* d_in, const int* in_sizes, int n_in,
                              void* d_out, int out_size, void* d_ws, size_t ws_size,
                              hipStream_t stream) {
    const float* x  = (const float*)d_in[0];
    const float* W1 = (const float*)d_in[1];
    const float* b1 = (const float*)d_in[2];
    const float* W2 = (const float*)d_in[3];
    const float* b2 = (const float*)d_in[4];
    const int*   ei = (const int*)d_in[5];

    const int N = in_sizes[0] / 16;
    const int E = in_sizes[5] / 2;
    const int* row = ei;
    const int* col = ei + E;
    const int K = (N + BIN_SIZE - 1) >> BIN_SHIFT;  // 1954 for N=500K

    float* ws   = (float*)d_ws;
    float* dinv = ws;                              // N floats
    half8* g0   = (half8*)(ws + (size_t)N);        // 4N floats worth; also binsort scratch
    half2v* g1  = (half2v*)(ws + (size_t)5 * N);   // N floats worth
    float* accA = ws + (size_t)6 * N;              // 8N floats (phase partials)
    int* keyptr = (int*)(ws + (size_t)14 * N);     // 4N+1 ints
    int*   meta = (int*)(ws + (size_t)18 * N + 8);
    int* ghist      = meta;                        // MAXK ints
    int* binBase    = meta + MAXK;                 // MAXK+1 ints (padded)
    int* scratchCur = meta + 2 * MAXK + 16;        // 1 int
    unsigned* packed = (unsigned*)(meta + 3 * MAXK);          // E uints
    int* cntB = (int*)(packed + E);                // MAXK*NBLK_EDGE ints
    int* cntT = cntB + (size_t)MAXK * NBLK_EDGE;   // MAXK*NBLK_EDGE ints

    float* out = (float*)d_out;

    const int gN = (N + TPB - 1) / TPB;
    const int chunk = (E + NBLK_EDGE - 1) / NBLK_EDGE;  // <= CHUNKE

    k_zero_int   <<<1, 64, 0, stream>>>(scratchCur, 1);
    k_hist       <<<NBLK_EDGE, TPB, 0, stream>>>(col, E, chunk, K, cntB, cntT);
    k_colscan    <<<K, 256, 0, stream>>>(cntT, ghist);
    k_scan       <<<1, 1024, 0, stream>>>(ghist, K, binBase);
    k_reorder    <<<NBLK_EDGE, TPB, 0, stream>>>(row, col, E, chunk, K,
                                                 binBase, cntB, cntT, packed);
    k_binsort_deg<<<K, NKEY, 0, stream>>>(packed, binBase, (unsigned*)g0, scratchCur,
                                          dinv, keyptr, N, E, K);
    k_node1      <<<gN, TPB, 0, stream>>>(x, W1, dinv, g0, N);
    for (int q = 0; q < 4; ++q)
        k_gather1_phase<<<gN, TPB, 0, stream>>>(packed, keyptr, g0, dinv, b1, W2,
                                                accA, g1, N, q);
    k_gather2_final<<<gN, TPB, 0, stream>>>(packed, keyptr, g1, dinv, b2, out, N);
}

// Round 10
// 379.597 us; speedup vs baseline: 1.2164x; 1.2164x over previous
//
#include <hip/hip_runtime.h>

#define TPB 256
#define NBLK_EDGE 1024         // blocks for hist/reorder; chunking must match between them
#define CHUNKE 8192            // max edges per reorder block
#define BIN_SHIFT 9
#define BIN_SIZE 512           // nodes per bin
#define MAXK 1024              // max bins (N=500K -> K=977)
#define ROW_BITS 19            // N=500,000 < 2^19
#define ROW_MASK ((1u << ROW_BITS) - 1)
#define Q_SHIFT 17             // source quarter = row>>17 (131072 nodes = 2.1MB of g0, fits 4MiB L2)
#define NKEY 2048              // binsort keys: (lc<<2)|quarter
#define CAP 12288              // binsort LDS buf2 capacity; mean bin = 8189 edges (+45 sigma)

typedef _Float16 half8  __attribute__((ext_vector_type(8)));
typedef _Float16 half2v __attribute__((ext_vector_type(2)));

__global__ void k_zero_int(int* __restrict__ p, int n) {
    int i = blockIdx.x * blockDim.x + threadIdx.x;
    if (i < n) p[i] = 0;
}

// Per-block LDS histogram of col>>BIN_SHIFT; persists per-block rows in both
// layouts: cntB (block-major, reload in k_reorder) and cntT (bin-major, for
// k_colscan). No global atomics.
__global__ void k_hist(const int* __restrict__ col, int E, int chunk, int K,
                       int* __restrict__ cntB, int* __restrict__ cntT) {
    __shared__ int lh[MAXK];
    int blk = blockIdx.x;
    for (int k = threadIdx.x; k < MAXK; k += blockDim.x) lh[k] = 0;
    __syncthreads();
    int s = blk * chunk, e_ = min(s + chunk, E);
    for (int e = s + threadIdx.x; e < e_; e += blockDim.x)
        atomicAdd(&lh[col[e] >> BIN_SHIFT], 1);
    __syncthreads();
    for (int k = threadIdx.x; k < MAXK; k += blockDim.x) {
        int v = lh[k];
        cntB[(size_t)blk * MAXK + k] = v;
        cntT[(size_t)k * NBLK_EDGE + blk] = v;
    }
}

// Per-bin exclusive scan over the NBLK_EDGE per-block counts (in-place) and
// per-bin total -> ghist. One block per bin, coalesced row access.
__global__ void k_colscan(int* __restrict__ cntT, int* __restrict__ ghist) {
    __shared__ int part[256];
    int b = blockIdx.x, tid = threadIdx.x;
    size_t base = (size_t)b * NBLK_EDGE;
    int t4 = tid * 4;
    int c0 = cntT[base + t4], c1 = cntT[base + t4 + 1],
        c2 = cntT[base + t4 + 2], c3 = cntT[base + t4 + 3];
    int sum = c0 + c1 + c2 + c3;
    part[tid] = sum;
    __syncthreads();
    for (int off = 1; off < 256; off <<= 1) {
        int v = (tid >= off) ? part[tid - off] : 0;
        __syncthreads();
        part[tid] += v;
        __syncthreads();
    }
    int excl = part[tid] - sum;
    cntT[base + t4]     = excl;
    cntT[base + t4 + 1] = excl + c0;
    cntT[base + t4 + 2] = excl + c0 + c1;
    cntT[base + t4 + 3] = excl + c0 + c1 + c2;
    if (tid == 255) ghist[b] = part[255];  // bin total
}

// Exclusive scan over K<=MAXK bins (single block of MAXK threads).
__global__ void k_scan(const int* __restrict__ ghist, int K, int* __restrict__ binBase) {
    __shared__ int tmp[MAXK];
    int tid = threadIdx.x;
    int val = (tid < K) ? ghist[tid] : 0;
    tmp[tid] = val;
    __syncthreads();
    for (int off = 1; off < MAXK; off <<= 1) {
        int v = (tid >= off) ? tmp[tid - off] : 0;
        __syncthreads();
        tmp[tid] += v;
        __syncthreads();
    }
    int incl = tmp[tid];
    if (tid < K) binBase[tid] = incl - val;
    if (tid == K - 1) binBase[K] = incl;  // == E
}

// Reorder with LOCAL SORT: place the block's chunk bin-sorted in LDS, then
// write out in contiguous per-bin runs so stores coalesce. Placement bases are
// precomputed (binBase + scanned cntT): no global atomics. 512 threads,
// 62KB LDS -> 2 blocks/CU, 16 waves.
__global__ void __launch_bounds__(512) k_reorder(
        const int* __restrict__ row, const int* __restrict__ col,
        int E, int chunk, int K,
        const int* __restrict__ binBase, const int* __restrict__ cntB,
        const int* __restrict__ cntT, unsigned* __restrict__ packed) {
    __shared__ unsigned sorted[CHUNKE];       // 32 KB
    __shared__ unsigned short sbin[CHUNKE];   // 16 KB
    __shared__ int lcur[MAXK], lbase[MAXK], gbase[MAXK];  // 12 KB
    __shared__ int part[512];
    int blk = blockIdx.x, tid = threadIdx.x;
    int s = blk * chunk, e_ = min(s + chunk, E), len = e_ - s;
    // local exclusive scan of this block's per-bin counts (2 keys/thread)
    int t2 = tid * 2;
    size_t bb = (size_t)blk * MAXK;
    int c0 = cntB[bb + t2], c1 = cntB[bb + t2 + 1];
    int sum = c0 + c1;
    part[tid] = sum;
    __syncthreads();
    for (int off = 1; off < 512; off <<= 1) {
        int v = (tid >= off) ? part[tid - off] : 0;
        __syncthreads();
        part[tid] += v;
        __syncthreads();
    }
    int run = part[tid] - sum;
    lbase[t2] = run;          lcur[t2] = run;
    lbase[t2 + 1] = run + c0; lcur[t2 + 1] = run + c0;
    for (int k = tid; k < K; k += blockDim.x)
        gbase[k] = binBase[k] + cntT[(size_t)k * NBLK_EDGE + blk];
    __syncthreads();
    // placement: bin-sorted staging in LDS (1 LDS atomic per edge)
    for (int i = tid; i < len; i += blockDim.x) {
        int cc = col[s + i];
        int b = cc >> BIN_SHIFT;
        int slot = atomicAdd(&lcur[b], 1);
        sorted[slot] = ((unsigned)(cc & (BIN_SIZE - 1)) << ROW_BITS) | (unsigned)row[s + i];
        sbin[slot] = (unsigned short)b;
    }
    __syncthreads();
    // coalesced run write-out
    for (int i = tid; i < len; i += blockDim.x) {
        int b = sbin[i];
        packed[gbase[b] + (i - lbase[b])] = sorted[i];
    }
}

// Counting sort by composite key (dest node, src quarter) within each bin.
// cnt gives per-node degree (dinv) AND per-(node,quarter) segment bases
// (keyptr). v2: no staging on the count pass; placement goes into LDS buf2 and
// the final write-back to packed is LINEAR (coalesced) — no scattered global
// writes. Oversized bins (>CAP) fall back to global-scratch staging.
__global__ void __launch_bounds__(1024) k_binsort_deg(
        unsigned* __restrict__ packed, const int* __restrict__ binBase,
        unsigned* __restrict__ scratch, int* __restrict__ scratchCur,
        float* __restrict__ dinv, int* __restrict__ keyptr, int N, int E, int K) {
    __shared__ unsigned buf2[CAP];     // 48 KB (sorted staging for coalesced writeback)
    __shared__ int cnt[NKEY], cur[NKEY];
    __shared__ int part[1024];
    __shared__ int sbShared;
    int tid = threadIdx.x;
    int bin = blockIdx.x;
    int s = binBase[bin], t = binBase[bin + 1];
    int len = t - s;
    bool fast = (len <= CAP);
    cnt[tid] = 0;
    cnt[tid + 1024] = 0;
    if (!fast && tid == 0) sbShared = atomicAdd(scratchCur, len);
    __syncthreads();
    // pass 1: composite-key count (coalesced read, no staging)
    for (int i = tid; i < len; i += blockDim.x) {
        unsigned v = packed[s + i];
        int k = (int)((v >> ROW_BITS) << 2) | (int)((v & ROW_MASK) >> Q_SHIFT);
        atomicAdd(&cnt[k], 1);
    }
    __syncthreads();
    // exclusive scan of cnt (2 keys/thread), cnt preserved
    int t2 = tid * 2;
    int c0 = cnt[t2], c1 = cnt[t2 + 1];
    int sum = c0 + c1;
    part[tid] = sum;
    __syncthreads();
    for (int off = 1; off < 1024; off <<= 1) {
        int v = (tid >= off) ? part[tid - off] : 0;
        __syncthreads();
        part[tid] += v;
        __syncthreads();
    }
    int excl = part[tid] - sum;
    cur[t2] = excl;
    cur[t2 + 1] = excl + c0;
    int base = bin << BIN_SHIFT;
    // keyptr: per-(node,quarter) segment base; index (bin<<11)+k == 4*node+q
    if (base + (t2 >> 2) < N) keyptr[((size_t)bin << 11) + t2] = s + excl;
    if (base + ((t2 + 1) >> 2) < N) keyptr[((size_t)bin << 11) + t2 + 1] = s + excl + c0;
    if (tid < BIN_SIZE) {
        int node = base + tid;
        if (node < N) {
            int deg = cnt[4 * tid] + cnt[4 * tid + 1] + cnt[4 * tid + 2] + cnt[4 * tid + 3];
            dinv[node] = rsqrtf((float)(deg + 1));  // +1 self-loop
        }
    }
    if (bin == K - 1 && tid == 0) keyptr[(size_t)4 * N] = E;  // sentinel
    __syncthreads();
    if (fast) {
        // pass 2: re-read (L2-hot) -> place into LDS
        for (int i = tid; i < len; i += blockDim.x) {
            unsigned v = packed[s + i];
            int k = (int)((v >> ROW_BITS) << 2) | (int)((v & ROW_MASK) >> Q_SHIFT);
            int slot = atomicAdd(&cur[k], 1);
            buf2[slot] = v;
        }
        __syncthreads();
        // coalesced linear write-back
        for (int i = tid; i < len; i += blockDim.x) packed[s + i] = buf2[i];
    } else {
        unsigned* stg = scratch + sbShared;
        for (int i = tid; i < len; i += blockDim.x) stg[i] = packed[s + i];
        __threadfence();
        __syncthreads();
        for (int i = tid; i < len; i += blockDim.x) {
            unsigned v = stg[i];
            int k = (int)((v >> ROW_BITS) << 2) | (int)((v & ROW_MASK) >> Q_SHIFT);
            int slot = atomicAdd(&cur[k], 1);
            packed[s + slot] = v;
        }
    }
}

// g0 = f16(dinv * (x @ W1)) — pure per-node, no edge work.
__global__ void k_node1(const float* __restrict__ x, const float* __restrict__ W1,
                        const float* __restrict__ dinv_arr, half8* __restrict__ g0, int N) {
    int i = blockIdx.x * blockDim.x + threadIdx.x;
    if (i >= N) return;
    float di = dinv_arr[i];
    const float4* xv = (const float4*)(x + (size_t)i * 16);
    float4 a0 = xv[0], a1 = xv[1], a2 = xv[2], a3 = xv[3];
    float xl[16] = {a0.x, a0.y, a0.z, a0.w, a1.x, a1.y, a1.z, a1.w,
                    a2.x, a2.y, a2.z, a2.w, a3.x, a3.y, a3.z, a3.w};
    float h[8];
#pragma unroll
    for (int j = 0; j < 8; ++j) h[j] = 0.0f;
#pragma unroll
    for (int k = 0; k < 16; ++k) {
        float xk = xl[k];
#pragma unroll
        for (int j = 0; j < 8; ++j) h[j] += xk * W1[k * 8 + j];
    }
    half8 g;
#pragma unroll
    for (int j = 0; j < 8; ++j) g[j] = (_Float16)(di * h[j]);
    g0[i] = g;
}

// Phased CSR gather layer 1: phase q only gathers sources in quarter q
// (2.1MB g0 window -> per-XCD L2 resident). Partial sums carried in accA
// (coalesced f32). q==3 adds self-loop, applies dinv + MLP -> g1.
__global__ void k_gather1_phase(const unsigned* __restrict__ packed,
                                const int* __restrict__ keyptr,
                                const half8* __restrict__ g0,
                                const float* __restrict__ dinv_arr,
                                const float* __restrict__ b1,
                                const float* __restrict__ W2,
                                float* __restrict__ accA,
                                half2v* __restrict__ g1, int N, int q) {
    int i = blockIdx.x * blockDim.x + threadIdx.x;
    if (i >= N) return;
    int s = keyptr[4 * i + q], t = keyptr[4 * i + q + 1];
    float acc[8];
    if (q == 0) {
#pragma unroll
        for (int j = 0; j < 8; ++j) acc[j] = 0.0f;
    } else {
        const float4* av = (const float4*)(accA + (size_t)i * 8);
        float4 lo = av[0], hi = av[1];
        acc[0] = lo.x; acc[1] = lo.y; acc[2] = lo.z; acc[3] = lo.w;
        acc[4] = hi.x; acc[5] = hi.y; acc[6] = hi.z; acc[7] = hi.w;
    }
    int e = s;
    for (; e + 4 <= t; e += 4) {
        unsigned p0 = packed[e], p1 = packed[e + 1], p2 = packed[e + 2], p3 = packed[e + 3];
        half8 v0 = g0[p0 & ROW_MASK];
        half8 v1 = g0[p1 & ROW_MASK];
        half8 v2 = g0[p2 & ROW_MASK];
        half8 v3 = g0[p3 & ROW_MASK];
#pragma unroll
        for (int j = 0; j < 8; ++j)
            acc[j] += (float)v0[j] + (float)v1[j] + (float)v2[j] + (float)v3[j];
    }
    for (; e < t; ++e) {
        half8 v = g0[packed[e] & ROW_MASK];
#pragma unroll
        for (int j = 0; j < 8; ++j) acc[j] += (float)v[j];
    }
    if (q < 3) {
        float4* av = (float4*)(accA + (size_t)i * 8);
        av[0] = make_float4(acc[0], acc[1], acc[2], acc[3]);
        av[1] = make_float4(acc[4], acc[5], acc[6], acc[7]);
    } else {
        half8 self = g0[i];
        float di = dinv_arr[i];
        float o0 = 0.0f, o1 = 0.0f;
#pragma unroll
        for (int j = 0; j < 8; ++j) {
            float hj = fmaxf(di * (acc[j] + (float)self[j]) + b1[j], 0.0f);
            o0 += hj * W2[j * 2 + 0];
            o1 += hj * W2[j * 2 + 1];
        }
        half2v g;
        g.x = (_Float16)(di * o0);
        g.y = (_Float16)(di * o1);
        g1[i] = g;
    }
}

// CSR gather layer 2 (g1 = 2MB, L2-resident) fused with log-softmax epilogue.
__global__ void k_gather2_final(const unsigned* __restrict__ packed,
                                const int* __restrict__ keyptr,
                                const half2v* __restrict__ g1,
                                const float* __restrict__ dinv_arr,
                                const float* __restrict__ b2,
                                float* __restrict__ out, int N) {
    int i = blockIdx.x * blockDim.x + threadIdx.x;
    if (i >= N) return;
    int s = keyptr[4 * i], t = keyptr[4 * i + 4];
    half2v sg = g1[i];
    float a0 = (float)sg.x, a1 = (float)sg.y;  // self-loop
    int e = s;
    for (; e + 4 <= t; e += 4) {
        unsigned p0 = packed[e], p1 = packed[e + 1], p2 = packed[e + 2], p3 = packed[e + 3];
        half2v v0 = g1[p0 & ROW_MASK];
        half2v v1 = g1[p1 & ROW_MASK];
        half2v v2 = g1[p2 & ROW_MASK];
        half2v v3 = g1[p3 & ROW_MASK];
        a0 += (float)v0.x + (float)v1.x + (float)v2.x + (float)v3.x;
        a1 += (float)v0.y + (float)v1.y + (float)v2.y + (float)v3.y;
    }
    for (; e < t; ++e) {
        half2v v = g1[packed[e] & ROW_MASK];
        a0 += (float)v.x;
        a1 += (float)v.y;
    }
    float di = dinv_arr[i];
    float o0 = di * a0 + b2[0];
    float o1 = di * a1 + b2[1];
    float m = fmaxf(o0, o1);
    float lse = m + logf(expf(o0 - m) + expf(o1 - m));
    ((float2*)out)[i] = make_float2(o0 - lse, o1 - lse);
}

extern "C" void kernel_launch(void* const* d_in, const int* in_sizes, int n_in,
                              void* d_out, int out_size, void* d_ws, size_t ws_size,
                              hipStream_t stream) {
    const float* x  = (const float*)d_in[0];
    const float* W1 = (const float*)d_in[1];
    const float* b1 = (const float*)d_in[2];
    const float* W2 = (const float*)d_in[3];
    const float* b2 = (const float*)d_in[4];
    const int*   ei = (const int*)d_in[5];

    const int N = in_sizes[0] / 16;
    const int E = in_sizes[5] / 2;
    const int* row = ei;
    const int* col = ei + E;
    const int K = (N + BIN_SIZE - 1) >> BIN_SHIFT;  // 977 for N=500K

    float* ws   = (float*)d_ws;
    float* dinv = ws;                              // N floats
    half8* g0   = (half8*)(ws + (size_t)N);        // 4N floats worth; also binsort scratch
    half2v* g1  = (half2v*)(ws + (size_t)5 * N);   // N floats worth
    float* accA = ws + (size_t)6 * N;              // 8N floats (phase partials)
    int* keyptr = (int*)(ws + (size_t)14 * N);     // 4N+1 ints
    int*   meta = (int*)(ws + (size_t)18 * N + 8);
    int* ghist      = meta;                        // MAXK ints
    int* binBase    = meta + MAXK;                 // MAXK+1 ints (padded)
    int* scratchCur = meta + 2 * MAXK + 16;        // 1 int
    unsigned* packed = (unsigned*)(meta + 3 * MAXK);          // E uints
    int* cntB = (int*)(packed + E);                // MAXK*NBLK_EDGE ints
    int* cntT = cntB + (size_t)MAXK * NBLK_EDGE;   // MAXK*NBLK_EDGE ints

    float* out = (float*)d_out;

    const int gN = (N + TPB - 1) / TPB;
    const int chunk = (E + NBLK_EDGE - 1) / NBLK_EDGE;  // <= CHUNKE

    k_zero_int   <<<1, 64, 0, stream>>>(scratchCur, 1);
    k_hist       <<<NBLK_EDGE, TPB, 0, stream>>>(col, E, chunk, K, cntB, cntT);
    k_colscan    <<<K, 256, 0, stream>>>(cntT, ghist);
    k_scan       <<<1, MAXK, 0, stream>>>(ghist, K, binBase);
    k_reorder    <<<NBLK_EDGE, 512, 0, stream>>>(row, col, E, chunk, K,
                                                 binBase, cntB, cntT, packed);
    k_binsort_deg<<<K, 1024, 0, stream>>>(packed, binBase, (unsigned*)g0, scratchCur,
                                          dinv, keyptr, N, E, K);
    k_node1      <<<gN, TPB, 0, stream>>>(x, W1, dinv, g0, N);
    for (int q = 0; q < 4; ++q)
        k_gather1_phase<<<gN, TPB, 0, stream>>>(packed, keyptr, g0, dinv, b1, W2,
                                                accA, g1, N, q);
    k_gather2_final<<<gN, TPB, 0, stream>>>(packed, keyptr, g1, dinv, b2, out, N);
}

// Round 11
// 371.137 us; speedup vs baseline: 1.2441x; 1.0228x over previous
//
#include <hip/hip_runtime.h>

#define TPB 256
#define NBLK_EDGE 1024         // blocks for hist/reorder; chunking must match between them
#define CHUNKE 8192            // max edges per reorder block
#define BIN_SHIFT 9
#define BIN_SIZE 512           // nodes per bin
#define MAXK 1024              // max bins (N=500K -> K=977)
#define ROW_BITS 19            // N=500,000 < 2^19
#define ROW_MASK ((1u << ROW_BITS) - 1)
#define Q_SHIFT 17             // source quarter = row>>17 (131072 nodes = 2.1MB of g0, fits 4MiB L2)
#define NKEY 2048              // binsort keys: (lc<<2)|quarter
#define CAP 12288              // binsort LDS buf2 capacity; mean bin = 8189 edges (+45 sigma)

typedef _Float16 half8  __attribute__((ext_vector_type(8)));
typedef _Float16 half2v __attribute__((ext_vector_type(2)));

// Per-block LDS histogram of col>>BIN_SHIFT; persists per-block rows in both
// layouts: cntB (block-major, reload in k_reorder) and cntT (bin-major, for
// k_colscan). No global atomics.
__global__ void k_hist(const int* __restrict__ col, int E, int chunk, int K,
                       int* __restrict__ cntB, int* __restrict__ cntT) {
    __shared__ int lh[MAXK];
    int blk = blockIdx.x;
    for (int k = threadIdx.x; k < MAXK; k += blockDim.x) lh[k] = 0;
    __syncthreads();
    int s = blk * chunk, e_ = min(s + chunk, E);
    for (int e = s + threadIdx.x; e < e_; e += blockDim.x)
        atomicAdd(&lh[col[e] >> BIN_SHIFT], 1);
    __syncthreads();
    for (int k = threadIdx.x; k < MAXK; k += blockDim.x) {
        int v = lh[k];
        cntB[(size_t)blk * MAXK + k] = v;
        cntT[(size_t)k * NBLK_EDGE + blk] = v;
    }
}

// Per-bin exclusive scan over the NBLK_EDGE per-block counts (in-place) and
// per-bin total -> ghist. One block per bin, coalesced row access.
__global__ void k_colscan(int* __restrict__ cntT, int* __restrict__ ghist) {
    __shared__ int part[256];
    int b = blockIdx.x, tid = threadIdx.x;
    size_t base = (size_t)b * NBLK_EDGE;
    int t4 = tid * 4;
    int c0 = cntT[base + t4], c1 = cntT[base + t4 + 1],
        c2 = cntT[base + t4 + 2], c3 = cntT[base + t4 + 3];
    int sum = c0 + c1 + c2 + c3;
    part[tid] = sum;
    __syncthreads();
    for (int off = 1; off < 256; off <<= 1) {
        int v = (tid >= off) ? part[tid - off] : 0;
        __syncthreads();
        part[tid] += v;
        __syncthreads();
    }
    int excl = part[tid] - sum;
    cntT[base + t4]     = excl;
    cntT[base + t4 + 1] = excl + c0;
    cntT[base + t4 + 2] = excl + c0 + c1;
    cntT[base + t4 + 3] = excl + c0 + c1 + c2;
    if (tid == 255) ghist[b] = part[255];  // bin total
}

// Exclusive scan over K<=MAXK bins (single block of MAXK threads).
// Also zeroes the oversized-bin scratch ticket (folds the old k_zero_int).
__global__ void k_scan(const int* __restrict__ ghist, int K, int* __restrict__ binBase,
                       int* __restrict__ scratchCur) {
    __shared__ int tmp[MAXK];
    int tid = threadIdx.x;
    if (tid == 0) *scratchCur = 0;
    int val = (tid < K) ? ghist[tid] : 0;
    tmp[tid] = val;
    __syncthreads();
    for (int off = 1; off < MAXK; off <<= 1) {
        int v = (tid >= off) ? tmp[tid - off] : 0;
        __syncthreads();
        tmp[tid] += v;
        __syncthreads();
    }
    int incl = tmp[tid];
    if (tid < K) binBase[tid] = incl - val;
    if (tid == K - 1) binBase[K] = incl;  // == E
}

// Reorder with LOCAL SORT: place the block's chunk bin-sorted in LDS, then
// write out in contiguous per-bin runs so stores coalesce. Placement bases are
// precomputed (binBase + scanned cntT): no global atomics. 1024 threads,
// 64KB LDS -> 2 blocks/CU -> 32 waves/CU (full occupancy).
__global__ void __launch_bounds__(1024) k_reorder(
        const int* __restrict__ row, const int* __restrict__ col,
        int E, int chunk, int K,
        const int* __restrict__ binBase, const int* __restrict__ cntB,
        const int* __restrict__ cntT, unsigned* __restrict__ packed) {
    __shared__ unsigned sorted[CHUNKE];       // 32 KB
    __shared__ unsigned short sbin[CHUNKE];   // 16 KB
    __shared__ int lcur[MAXK], lbase[MAXK], gbase[MAXK];  // 12 KB
    __shared__ int part[1024];                // 4 KB
    int blk = blockIdx.x, tid = threadIdx.x;
    int s = blk * chunk, e_ = min(s + chunk, E), len = e_ - s;
    // local exclusive scan of this block's per-bin counts (1 key/thread)
    size_t bb = (size_t)blk * MAXK;
    int c0 = cntB[bb + tid];
    part[tid] = c0;
    __syncthreads();
    for (int off = 1; off < 1024; off <<= 1) {
        int v = (tid >= off) ? part[tid - off] : 0;
        __syncthreads();
        part[tid] += v;
        __syncthreads();
    }
    int excl = part[tid] - c0;
    lbase[tid] = excl;
    lcur[tid] = excl;
    gbase[tid] = binBase[tid] + cntT[(size_t)tid * NBLK_EDGE + blk];
    __syncthreads();
    // placement: bin-sorted staging in LDS (1 LDS atomic per edge)
    for (int i = tid; i < len; i += blockDim.x) {
        int cc = col[s + i];
        int b = cc >> BIN_SHIFT;
        int slot = atomicAdd(&lcur[b], 1);
        sorted[slot] = ((unsigned)(cc & (BIN_SIZE - 1)) << ROW_BITS) | (unsigned)row[s + i];
        sbin[slot] = (unsigned short)b;
    }
    __syncthreads();
    // coalesced run write-out
    for (int i = tid; i < len; i += blockDim.x) {
        int b = sbin[i];
        packed[gbase[b] + (i - lbase[b])] = sorted[i];
    }
}

// Counting sort by composite key (dest node, src quarter) within each bin ->
// keyptr (per-(node,quarter) segment bases) + dinv. Placement goes into LDS
// buf2, final write-back LINEAR (coalesced). Oversized bins (>CAP) stage via
// global scratch (accA region, ticketed). FUSED TAIL: threads 0..511 compute
// g0 = f16(dinv * (x @ W1)) for the bin's nodes (degree already in-register).
__global__ void __launch_bounds__(1024) k_binsort_deg(
        unsigned* __restrict__ packed, const int* __restrict__ binBase,
        unsigned* __restrict__ scratch, int* __restrict__ scratchCur,
        const float* __restrict__ x, const float* __restrict__ W1,
        float* __restrict__ dinv, half8* __restrict__ g0,
        int* __restrict__ keyptr, int N, int E, int K) {
    __shared__ unsigned buf2[CAP];     // 48 KB (sorted staging for coalesced writeback)
    __shared__ int cnt[NKEY], cur[NKEY];
    __shared__ int part[1024];
    __shared__ int sbShared;
    int tid = threadIdx.x;
    int bin = blockIdx.x;
    int s = binBase[bin], t = binBase[bin + 1];
    int len = t - s;
    bool fast = (len <= CAP);
    cnt[tid] = 0;
    cnt[tid + 1024] = 0;
    if (!fast && tid == 0) sbShared = atomicAdd(scratchCur, len);
    __syncthreads();
    // pass 1: composite-key count (coalesced read, no staging)
    for (int i = tid; i < len; i += blockDim.x) {
        unsigned v = packed[s + i];
        int k = (int)((v >> ROW_BITS) << 2) | (int)((v & ROW_MASK) >> Q_SHIFT);
        atomicAdd(&cnt[k], 1);
    }
    __syncthreads();
    // exclusive scan of cnt (2 keys/thread), cnt preserved
    int t2 = tid * 2;
    int c0 = cnt[t2], c1 = cnt[t2 + 1];
    int sum = c0 + c1;
    part[tid] = sum;
    __syncthreads();
    for (int off = 1; off < 1024; off <<= 1) {
        int v = (tid >= off) ? part[tid - off] : 0;
        __syncthreads();
        part[tid] += v;
        __syncthreads();
    }
    int excl = part[tid] - sum;
    cur[t2] = excl;
    cur[t2 + 1] = excl + c0;
    int base = bin << BIN_SHIFT;
    // keyptr: per-(node,quarter) segment base; index (bin<<11)+k == 4*node+q
    if (base + (t2 >> 2) < N) keyptr[((size_t)bin << 11) + t2] = s + excl;
    if (base + ((t2 + 1) >> 2) < N) keyptr[((size_t)bin << 11) + t2 + 1] = s + excl + c0;
    float di = 0.0f;
    int node = base + tid;
    if (tid < BIN_SIZE && node < N) {
        int deg = cnt[4 * tid] + cnt[4 * tid + 1] + cnt[4 * tid + 2] + cnt[4 * tid + 3];
        di = rsqrtf((float)(deg + 1));  // +1 self-loop
        dinv[node] = di;
    }
    if (bin == K - 1 && tid == 0) keyptr[(size_t)4 * N] = E;  // sentinel
    __syncthreads();
    if (fast) {
        // pass 2: re-read (L2-hot) -> place into LDS
        for (int i = tid; i < len; i += blockDim.x) {
            unsigned v = packed[s + i];
            int k = (int)((v >> ROW_BITS) << 2) | (int)((v & ROW_MASK) >> Q_SHIFT);
            int slot = atomicAdd(&cur[k], 1);
            buf2[slot] = v;
        }
        __syncthreads();
        // coalesced linear write-back
        for (int i = tid; i < len; i += blockDim.x) packed[s + i] = buf2[i];
    } else {
        unsigned* stg = scratch + sbShared;
        for (int i = tid; i < len; i += blockDim.x) stg[i] = packed[s + i];
        __threadfence();
        __syncthreads();
        for (int i = tid; i < len; i += blockDim.x) {
            unsigned v = stg[i];
            int k = (int)((v >> ROW_BITS) << 2) | (int)((v & ROW_MASK) >> Q_SHIFT);
            int slot = atomicAdd(&cur[k], 1);
            packed[s + slot] = v;
        }
    }
    // fused node1 tail: g0 = f16(dinv * (x @ W1)) for this bin's nodes
    if (tid < BIN_SIZE && node < N) {
        const float4* xv = (const float4*)(x + (size_t)node * 16);
        float h[8];
#pragma unroll
        for (int j = 0; j < 8; ++j) h[j] = 0.0f;
#pragma unroll
        for (int kk = 0; kk < 4; ++kk) {
            float4 a = xv[kk];
            int kb = kk * 4;
#pragma unroll
            for (int j = 0; j < 8; ++j)
                h[j] += a.x * W1[kb * 8 + j] + a.y * W1[(kb + 1) * 8 + j]
                      + a.z * W1[(kb + 2) * 8 + j] + a.w * W1[(kb + 3) * 8 + j];
        }
        half8 g;
#pragma unroll
        for (int j = 0; j < 8; ++j) g[j] = (_Float16)(di * h[j]);
        g0[node] = g;
    }
}

// Phased CSR gather layer 1: phase q only gathers sources in quarter q
// (2.1MB g0 window -> per-XCD L2 resident). Partial sums carried in accA
// (coalesced f32). q==3 adds self-loop, applies dinv + MLP -> g1.
__global__ void k_gather1_phase(const unsigned* __restrict__ packed,
                                const int* __restrict__ keyptr,
                                const half8* __restrict__ g0,
                                const float* __restrict__ dinv_arr,
                                const float* __restrict__ b1,
                                const float* __restrict__ W2,
                                float* __restrict__ accA,
                                half2v* __restrict__ g1, int N, int q) {
    int i = blockIdx.x * blockDim.x + threadIdx.x;
    if (i >= N) return;
    int s = keyptr[4 * i + q], t = keyptr[4 * i + q + 1];
    float acc[8];
    if (q == 0) {
#pragma unroll
        for (int j = 0; j < 8; ++j) acc[j] = 0.0f;
    } else {
        const float4* av = (const float4*)(accA + (size_t)i * 8);
        float4 lo = av[0], hi = av[1];
        acc[0] = lo.x; acc[1] = lo.y; acc[2] = lo.z; acc[3] = lo.w;
        acc[4] = hi.x; acc[5] = hi.y; acc[6] = hi.z; acc[7] = hi.w;
    }
    int e = s;
    for (; e + 4 <= t; e += 4) {
        unsigned p0 = packed[e], p1 = packed[e + 1], p2 = packed[e + 2], p3 = packed[e + 3];
        half8 v0 = g0[p0 & ROW_MASK];
        half8 v1 = g0[p1 & ROW_MASK];
        half8 v2 = g0[p2 & ROW_MASK];
        half8 v3 = g0[p3 & ROW_MASK];
#pragma unroll
        for (int j = 0; j < 8; ++j)
            acc[j] += (float)v0[j] + (float)v1[j] + (float)v2[j] + (float)v3[j];
    }
    for (; e < t; ++e) {
        half8 v = g0[packed[e] & ROW_MASK];
#pragma unroll
        for (int j = 0; j < 8; ++j) acc[j] += (float)v[j];
    }
    if (q < 3) {
        float4* av = (float4*)(accA + (size_t)i * 8);
        av[0] = make_float4(acc[0], acc[1], acc[2], acc[3]);
        av[1] = make_float4(acc[4], acc[5], acc[6], acc[7]);
    } else {
        half8 self = g0[i];
        float di = dinv_arr[i];
        float o0 = 0.0f, o1 = 0.0f;
#pragma unroll
        for (int j = 0; j < 8; ++j) {
            float hj = fmaxf(di * (acc[j] + (float)self[j]) + b1[j], 0.0f);
            o0 += hj * W2[j * 2 + 0];
            o1 += hj * W2[j * 2 + 1];
        }
        half2v g;
        g.x = (_Float16)(di * o0);
        g.y = (_Float16)(di * o1);
        g1[i] = g;
    }
}

// CSR gather layer 2 (g1 = 2MB, L2-resident) fused with log-softmax epilogue.
__global__ void k_gather2_final(const unsigned* __restrict__ packed,
                                const int* __restrict__ keyptr,
                                const half2v* __restrict__ g1,
                                const float* __restrict__ dinv_arr,
                                const float* __restrict__ b2,
                                float* __restrict__ out, int N) {
    int i = blockIdx.x * blockDim.x + threadIdx.x;
    if (i >= N) return;
    int s = keyptr[4 * i], t = keyptr[4 * i + 4];
    half2v sg = g1[i];
    float a0 = (float)sg.x, a1 = (float)sg.y;  // self-loop
    int e = s;
    for (; e + 4 <= t; e += 4) {
        unsigned p0 = packed[e], p1 = packed[e + 1], p2 = packed[e + 2], p3 = packed[e + 3];
        half2v v0 = g1[p0 & ROW_MASK];
        half2v v1 = g1[p1 & ROW_MASK];
        half2v v2 = g1[p2 & ROW_MASK];
        half2v v3 = g1[p3 & ROW_MASK];
        a0 += (float)v0.x + (float)v1.x + (float)v2.x + (float)v3.x;
        a1 += (float)v0.y + (float)v1.y + (float)v2.y + (float)v3.y;
    }
    for (; e < t; ++e) {
        half2v v = g1[packed[e] & ROW_MASK];
        a0 += (float)v.x;
        a1 += (float)v.y;
    }
    float di = dinv_arr[i];
    float o0 = di * a0 + b2[0];
    float o1 = di * a1 + b2[1];
    float m = fmaxf(o0, o1);
    float lse = m + logf(expf(o0 - m) + expf(o1 - m));
    ((float2*)out)[i] = make_float2(o0 - lse, o1 - lse);
}

extern "C" void kernel_launch(void* const* d_in, const int* in_sizes, int n_in,
                              void* d_out, int out_size, void* d_ws, size_t ws_size,
                              hipStream_t stream) {
    const float* x  = (const float*)d_in[0];
    const float* W1 = (const float*)d_in[1];
    const float* b1 = (const float*)d_in[2];
    const float* W2 = (const float*)d_in[3];
    const float* b2 = (const float*)d_in[4];
    const int*   ei = (const int*)d_in[5];

    const int N = in_sizes[0] / 16;
    const int E = in_sizes[5] / 2;
    const int* row = ei;
    const int* col = ei + E;
    const int K = (N + BIN_SIZE - 1) >> BIN_SHIFT;  // 977 for N=500K

    float* ws   = (float*)d_ws;
    float* dinv = ws;                              // N floats
    half8* g0   = (half8*)(ws + (size_t)N);        // 4N floats worth
    half2v* g1  = (half2v*)(ws + (size_t)5 * N);   // N floats worth
    float* accA = ws + (size_t)6 * N;              // 8N floats (phase partials);
                                                   //   also binsort oversized-bin scratch
    int* keyptr = (int*)(ws + (size_t)14 * N);     // 4N+1 ints
    int*   meta = (int*)(ws + (size_t)18 * N + 8);
    int* ghist      = meta;                        // MAXK ints
    int* binBase    = meta + MAXK;                 // MAXK+1 ints (padded)
    int* scratchCur = meta + 2 * MAXK + 16;        // 1 int
    unsigned* packed = (unsigned*)(meta + 3 * MAXK);          // E uints
    int* cntB = (int*)(packed + E);                // MAXK*NBLK_EDGE ints
    int* cntT = cntB + (size_t)MAXK * NBLK_EDGE;   // MAXK*NBLK_EDGE ints

    float* out = (float*)d_out;

    const int gN = (N + TPB - 1) / TPB;
    const int chunk = (E + NBLK_EDGE - 1) / NBLK_EDGE;  // <= CHUNKE

    k_hist       <<<NBLK_EDGE, TPB, 0, stream>>>(col, E, chunk, K, cntB, cntT);
    k_colscan    <<<K, 256, 0, stream>>>(cntT, ghist);
    k_scan       <<<1, MAXK, 0, stream>>>(ghist, K, binBase, scratchCur);
    k_reorder    <<<NBLK_EDGE, 1024, 0, stream>>>(row, col, E, chunk, K,
                                                  binBase, cntB, cntT, packed);
    k_binsort_deg<<<K, 1024, 0, stream>>>(packed, binBase, (unsigned*)accA, scratchCur,
                                          x, W1, dinv, g0, keyptr, N, E, K);
    for (int q = 0; q < 4; ++q)
        k_gather1_phase<<<gN, TPB, 0, stream>>>(packed, keyptr, g0, dinv, b1, W2,
                                                accA, g1, N, q);
    k_gather2_final<<<gN, TPB, 0, stream>>>(packed, keyptr, g1, dinv, b2, out, N);
}